// Round 6
// baseline (438.200 us; speedup 1.0000x reference)
//
#include <hip/hip_runtime.h>
#include <hip/hip_fp16.h>

typedef _Float16 f16;
typedef __attribute__((ext_vector_type(8)))  f16   f16x8;
typedef __attribute__((ext_vector_type(16))) float f32x16;
typedef __attribute__((ext_vector_type(4)))  float f32x4;
typedef __attribute__((ext_vector_type(2)))  unsigned int u32x2;
typedef unsigned int uint;
typedef unsigned short ushort;

#define MFMA16 __builtin_amdgcn_mfma_f32_32x32x16_f16
#define SCALE_Q 0.17677669529663687f   // 1/sqrt(32)

// LDS: region A = xn tile, region B = attention-out tile
#define XN_ROW   264                    // fp16 elems per row (256 + 8 pad; rows 16B-aligned, 4-way LDS conflict)
#define XN_BYTES (64 * XN_ROW * 2)      // 33792 B
#define AO_OFF   XN_BYTES
#define LDS_TOTAL (2 * XN_BYTES)        // 67584 B

#define Z16 {0.f,0.f,0.f,0.f,0.f,0.f,0.f,0.f,0.f,0.f,0.f,0.f,0.f,0.f,0.f,0.f}

__device__ __forceinline__ ushort f2h_bits(float f) {
    return __builtin_bit_cast(ushort, (f16)f);    // RTN
}
__device__ __forceinline__ uint pk2(float a, float b) {
    return (uint)f2h_bits(a) | ((uint)f2h_bits(b) << 16);
}

// Build an 8xf16 MFMA A/B fragment (elements c = 16*kss + 8*h5 + j, j=0..7, at
// lane col=l31) from an f32 C-fragment whose (col=l31, row) layout is
// row = (r&3) + 8*(r>>2) + 4*h5src. One half-exchange via shfl_xor(32). RTN pack.
__device__ __forceinline__ f16x8 build_frag(const f32x16 c, const int kss, const int h5) {
    const int kb8 = 8 * kss;
    const uint keep0 = pk2(c[kb8 + 4*h5 + 0], c[kb8 + 4*h5 + 1]);
    const uint keep1 = pk2(c[kb8 + 4*h5 + 2], c[kb8 + 4*h5 + 3]);
    const int  o     = kb8 + 4*(1 - h5);
    const uint send0 = pk2(c[o + 0], c[o + 1]);
    const uint send1 = pk2(c[o + 2], c[o + 3]);
    const uint recv0 = (uint)__shfl_xor((int)send0, 32, 64);
    const uint recv1 = (uint)__shfl_xor((int)send1, 32, 64);
    union { uint u[4]; f16x8 v; } A;
    A.u[0] = h5 ? recv0 : keep0;
    A.u[1] = h5 ? recv1 : keep1;
    A.u[2] = h5 ? keep0 : recv0;
    A.u[3] = h5 ? keep1 : recv1;
    return A.v;
}

// ---------------- prep: weights & bias into COALESCED fragment-tiled order ----------------
// qkv: dst[((rb*16 + ks)*64 + lane)*8 + j] = W[rb*32 + (lane&31)][ks*16 + (lane>>5)*8 + j]
//      rb 0..7 = q-heads (scaled), 8..15 = k, 16..23 = v.
// proj: same with h = rb (0..7).
// bias: dst[((((h*2+mt)*2+nt)*4 + q4)*64 + lane)*4 + j]
//       = table[ridx[(32nt + (lane&31))*64 + (32mt + 8q4 + j + 4*(lane>>5))]*8 + h]
__global__ void lwa_prep(const float* __restrict__ qkvw, const float* __restrict__ projw,
                         const float* __restrict__ table, const int* __restrict__ ridx,
                         ushort* __restrict__ wqs, ushort* __restrict__ wps, float* __restrict__ biasr)
{
    int i = blockIdx.x * 256 + threadIdx.x;
    if (i < 196608) {                       // qkv weights, fragment-tiled
        int j    = i & 7;
        int lane = (i >> 3) & 63;
        int ks   = (i >> 9) & 15;
        int rb   = i >> 13;
        int row  = rb * 32 + (lane & 31);
        int col  = ks * 16 + (lane >> 5) * 8 + j;
        float v = qkvw[row * 256 + col];
        if (rb < 8) v *= SCALE_Q;
        wqs[i] = f2h_bits(v);
    } else if (i < 262144) {                // proj weights, fragment-tiled
        int t    = i - 196608;
        int j    = t & 7;
        int lane = (t >> 3) & 63;
        int ks   = (t >> 9) & 15;
        int h    = t >> 13;
        int row  = h * 32 + (lane & 31);
        int col  = ks * 16 + (lane >> 5) * 8 + j;
        wps[t] = f2h_bits(projw[row * 256 + col]);
    } else {                                // bias, coalesced fragment order
        int t    = i - 262144;
        int j    = t & 3;
        int lane = (t >> 2) & 63;
        int q4   = (t >> 8) & 3;
        int nt   = (t >> 10) & 1;
        int mt   = (t >> 11) & 1;
        int h    = t >> 12;
        int qrow = 32 * nt + (lane & 31);
        int kv   = 32 * mt + 8 * q4 + j + 4 * (lane >> 5);
        biasr[t] = table[ridx[qrow * 64 + kv] * 8 + h];
    }
}

// ---------------- main: one block (1024 thr, 16 waves) per window; wave = (head, q-half) ----------------
__global__ __launch_bounds__(1024, 4) void lwa_main(
    const float* __restrict__ x, const float* __restrict__ nz,
    const float* __restrict__ gamma, const float* __restrict__ beta,
    const ushort* __restrict__ wqs, const ushort* __restrict__ wps,
    const float* __restrict__ biasr, const float* __restrict__ projb,
    float* __restrict__ out)
{
    __shared__ char smem[LDS_TOTAL];
    const int tid  = threadIdx.x;
    const int wid  = tid >> 6;       // 0..15
    const int lane = tid & 63;
    const int l31  = lane & 31;
    const int h5   = lane >> 5;
    const int h    = wid >> 1;       // head
    const int nt   = wid & 1;        // q-half (rows 32*nt .. 32*nt+31)
    const int w    = blockIdx.x;     // window
    const int bidx = w >> 8;
    const int kb   = h5 * 8;

    // ---- Phase 1: LN (64 rows, 16 threads/row) -> xn fp16 in LDS region A ----
    {
        const int p   = tid >> 4;
        const int sub = tid & 15;
        const float* xrow = x  + (size_t)w * 16384 + p * 256;
        const float* nrow = nz + (size_t)bidx * 16384 + p * 256;
        f32x4 v[4];
        float s = 0.f, ss = 0.f;
#pragma unroll
        for (int i = 0; i < 4; ++i) {
            const int c4 = sub + 16 * i;
            f32x4 xv = *(const f32x4*)(xrow + 4 * c4);
            f32x4 nv = *(const f32x4*)(nrow + 4 * c4);
            f32x4 t = xv * nv;
            v[i] = t;
            s  += t[0] + t[1] + t[2] + t[3];
            ss += t[0]*t[0] + t[1]*t[1] + t[2]*t[2] + t[3]*t[3];
        }
#pragma unroll
        for (int m = 1; m < 16; m <<= 1) { s += __shfl_xor(s, m, 64); ss += __shfl_xor(ss, m, 64); }
        const float mu = s * (1.f / 256.f);
        const float rs = rsqrtf(fmaxf(ss * (1.f / 256.f) - mu * mu, 0.f) + 1e-5f);
        char* xnrow = smem + (size_t)p * (XN_ROW * 2);
#pragma unroll
        for (int i = 0; i < 4; ++i) {
            const int c4 = sub + 16 * i;
            f32x4 g  = *(const f32x4*)(gamma + 4 * c4);
            f32x4 bb = *(const f32x4*)(beta  + 4 * c4);
            f32x4 t  = v[i];
            u32x2 pkv;
            pkv[0] = pk2((t[0]-mu)*rs*g[0] + bb[0], (t[1]-mu)*rs*g[1] + bb[1]);
            pkv[1] = pk2((t[2]-mu)*rs*g[2] + bb[2], (t[3]-mu)*rs*g[3] + bb[3]);
            *(u32x2*)(xnrow + c4 * 8) = pkv;
        }
    }
    __syncthreads();

    const char* xb = smem;

    // ---- Phase 2a: merged q(+half) & k(full) pass, 3-way MFMA ILP, coalesced weights ----
    f16x8 qf[2], kf[2][2];
    {
        const ushort* bqp = wqs + (size_t)(     h) * 16 * 512;   // 512 = 64 lanes * 8
        const ushort* bkp = wqs + (size_t)( 8 + h) * 16 * 512;
        f32x16 cq = Z16, ck0 = Z16, ck1 = Z16;
#pragma unroll 4
        for (int ks = 0; ks < 16; ++ks) {
            const int kk = ks * 16 + kb;
            f16x8 a0 = *(const f16x8*)(xb + ( l31            * XN_ROW + kk) * 2);
            f16x8 a1 = *(const f16x8*)(xb + ((32 + l31)      * XN_ROW + kk) * 2);
            f16x8 aq = *(const f16x8*)(xb + ((32 * nt + l31) * XN_ROW + kk) * 2);
            f16x8 bq = *(const f16x8*)(bqp + (ks * 64 + lane) * 8);
            f16x8 bk = *(const f16x8*)(bkp + (ks * 64 + lane) * 8);
            cq  = MFMA16(bq, aq, cq,  0, 0, 0);   // D[m=chan][n=q-pos(half)]
            ck0 = MFMA16(bk, a0, ck0, 0, 0, 0);   // D[m=chan][n=kv 0..31]
            ck1 = MFMA16(bk, a1, ck1, 0, 0, 0);   // D[m=chan][n=kv 32..63]
        }
        qf[0]    = build_frag(cq,  0, h5);
        qf[1]    = build_frag(cq,  1, h5);
        kf[0][0] = build_frag(ck0, 0, h5);
        kf[0][1] = build_frag(ck0, 1, h5);
        kf[1][0] = build_frag(ck1, 0, h5);
        kf[1][1] = build_frag(ck1, 1, h5);
    }

    // ---- Phase 3a: S^T (+bias), softmax over kv, pack P frags ----
    f16x8 pf[4];                     // kv chunks of 16
    {
        f32x16 st0 = Z16, st1 = Z16;
#pragma unroll
        for (int ks = 0; ks < 2; ++ks) {
            st0 = MFMA16(kf[0][ks], qf[ks], st0, 0, 0, 0);   // kv 0..31 x q-half
            st1 = MFMA16(kf[1][ks], qf[ks], st1, 0, 0, 0);   // kv 32..63
        }
        const float* bb = biasr + (size_t)(((h * 2 + 0) * 2 + nt) * 4) * 256;  // [q4][lane][4]
#pragma unroll
        for (int q4 = 0; q4 < 4; ++q4) {
            f32x4 b0 = *(const f32x4*)(bb + (q4 * 64 + lane) * 4);
            f32x4 b1 = *(const f32x4*)(bb + ((q4 + 8) * 64 + lane) * 4);   // mt=1 block is +2*4 q4-slots
#pragma unroll
            for (int j = 0; j < 4; ++j) {
                st0[4*q4+j] += b0[j];
                st1[4*q4+j] += b1[j];
            }
        }
        float mx = st0[0];
#pragma unroll
        for (int r = 0; r < 16; ++r) { mx = fmaxf(mx, st0[r]); mx = fmaxf(mx, st1[r]); }
        mx = fmaxf(mx, __shfl_xor(mx, 32, 64));
        float sum = 0.f;
#pragma unroll
        for (int r = 0; r < 16; ++r) {
            float e0 = __expf(st0[r] - mx);
            float e1 = __expf(st1[r] - mx);
            st0[r] = e0; st1[r] = e1;
            sum += e0 + e1;
        }
        sum += __shfl_xor(sum, 32, 64);
        const float rd = __builtin_amdgcn_rcpf(sum);
#pragma unroll
        for (int r = 0; r < 16; ++r) { st0[r] *= rd; st1[r] *= rd; }
        pf[0] = build_frag(st0, 0, h5);
        pf[1] = build_frag(st0, 1, h5);
        pf[2] = build_frag(st1, 0, h5);
        pf[3] = build_frag(st1, 1, h5);
    }

    // ---- Phase 2b: v pass (full), normal orientation ----
    f32x16 av0 = Z16, av1 = Z16;
    {
        const ushort* bvp = wqs + (size_t)(16 + h) * 16 * 512;
#pragma unroll 4
        for (int ks = 0; ks < 16; ++ks) {
            const int kk = ks * 16 + kb;
            f16x8 a0 = *(const f16x8*)(xb + ( l31       * XN_ROW + kk) * 2);
            f16x8 a1 = *(const f16x8*)(xb + ((32 + l31) * XN_ROW + kk) * 2);
            f16x8 bv = *(const f16x8*)(bvp + (ks * 64 + lane) * 8);
            av0 = MFMA16(a0, bv, av0, 0, 0, 0);   // D[m=pos 0..31][n=chan]
            av1 = MFMA16(a1, bv, av1, 0, 0, 0);   // D[m=pos 32..63][n=chan]
        }
    }

    // ---- Phase 3b: O = P·V (one 32x32 tile: this wave's q-half x head channels) ----
    f32x16 o = Z16;
    {
        f16x8 vf0 = build_frag(av0, 0, h5);
        o = MFMA16(pf[0], vf0, o, 0, 0, 0);
        f16x8 vf1 = build_frag(av0, 1, h5);
        o = MFMA16(pf[1], vf1, o, 0, 0, 0);
        f16x8 vf2 = build_frag(av1, 0, h5);
        o = MFMA16(pf[2], vf2, o, 0, 0, 0);
        f16x8 vf3 = build_frag(av1, 1, h5);
        o = MFMA16(pf[3], vf3, o, 0, 0, 0);
    }

    // write attention output to LDS region B
    {
        char* ao = smem + AO_OFF;
#pragma unroll
        for (int r = 0; r < 16; ++r) {
            const int row = 32 * nt + (r & 3) + 8 * (r >> 2) + 4 * h5;
            *(ushort*)(ao + (row * XN_ROW + h * 32 + l31) * 2) = f2h_bits(o[r]);
        }
    }
    __syncthreads();

    // ---- Phase 4: proj GEMM + bias (wave: rows 32nt tile, cols 32h tile) ----
    {
        const ushort* bwp = wps + (size_t)h * 16 * 512;
        const char* ao = smem + AO_OFF;
        f32x16 pa = Z16;
#pragma unroll 4
        for (int ks = 0; ks < 16; ++ks) {
            const int kk = ks * 16 + kb;
            f16x8 a0 = *(const f16x8*)(ao + ((32 * nt + l31) * XN_ROW + kk) * 2);
            f16x8 bw = *(const f16x8*)(bwp + (ks * 64 + lane) * 8);
            pa = MFMA16(a0, bw, pa, 0, 0, 0);
        }
        const float pb = projb[32 * h + l31];
        float* orow = out + (size_t)w * 16384;
#pragma unroll
        for (int r = 0; r < 16; ++r) {
            const int prow = 32 * nt + (r & 3) + 8 * (r >> 2) + 4 * h5;
            orow[(size_t)prow * 256 + 32 * h + l31] = pa[r] + pb;
        }
    }
}

extern "C" void kernel_launch(void* const* d_in, const int* in_sizes, int n_in,
                              void* d_out, int out_size, void* d_ws, size_t ws_size,
                              hipStream_t stream)
{
    const float* x     = (const float*)d_in[0];
    const float* nz    = (const float*)d_in[1];
    const float* gamma = (const float*)d_in[2];
    const float* beta  = (const float*)d_in[3];
    const float* qkvw  = (const float*)d_in[4];
    const float* projw = (const float*)d_in[5];
    const float* projb = (const float*)d_in[6];
    const float* table = (const float*)d_in[7];
    const int*   ridx  = (const int*)d_in[8];

    ushort* wqs   = (ushort*)d_ws;            // 196608 fp16, fragment-tiled
    ushort* wps   = wqs + 196608;             // 65536 fp16
    float*  biasr = (float*)(wps + 65536);    // 32768 f32

    lwa_prep<<<1152, 256, 0, stream>>>(qkvw, projw, table, ridx, wqs, wps, biasr);
    lwa_main<<<2048, 1024, 0, stream>>>(x, nz, gamma, beta, wqs, wps, biasr, projb,
                                        (float*)d_out);
}

// Round 7
// 244.778 us; speedup vs baseline: 1.7902x; 1.7902x over previous
//
#include <hip/hip_runtime.h>
#include <hip/hip_fp16.h>

typedef _Float16 f16;
typedef __attribute__((ext_vector_type(8)))  f16   f16x8;
typedef __attribute__((ext_vector_type(16))) float f32x16;
typedef __attribute__((ext_vector_type(4)))  float f32x4;
typedef __attribute__((ext_vector_type(2)))  unsigned int u32x2;
typedef unsigned int uint;
typedef unsigned short ushort;

#define MFMA16 __builtin_amdgcn_mfma_f32_32x32x16_f16
#define SCALE_Q 0.17677669529663687f   // 1/sqrt(32)

// ---- LDS plan (dynamic, 70656 B -> 2 blocks/CU) ----
// [0, 36864):  xn [64][264] fp16 (33792 B)   -> then vT [256][72] fp16 (36864 B) -> then ao [64][264]
// [36864, 70656): k [64][264] fp16 (33792 B), heads at col 32h
// row strides 264 f16 (132 dw == 4 mod 32: b128 column reads tile all banks) and
// 72 f16 (36 dw, 36/4 odd: same property).
#define XN_ROW   264
#define XN_BYTES (64 * XN_ROW * 2)      // 33792
#define VT_ROW   72
#define VT_OFF   0
#define K_OFF    36864                  // 256*72*2
#define AO_OFF   0
#define LDS_TOTAL (K_OFF + XN_BYTES)    // 70656

#define Z16 {0.f,0.f,0.f,0.f,0.f,0.f,0.f,0.f,0.f,0.f,0.f,0.f,0.f,0.f,0.f,0.f}

__device__ __forceinline__ ushort f2h_bits(float f) {
    return __builtin_bit_cast(ushort, (f16)f);    // RTN
}
__device__ __forceinline__ uint pk2(float a, float b) {
    return (uint)f2h_bits(a) | ((uint)f2h_bits(b) << 16);
}

// 8xf16 MFMA A/B fragment (elements c = 16*kss + 8*h5 + j at lane col=l31) from an
// f32 C-frag with row = (r&3) + 8*(r>>2) + 4*h5src. One shfl_xor(32) half-exchange.
__device__ __forceinline__ f16x8 build_frag(const f32x16 c, const int kss, const int h5) {
    const int kb8 = 8 * kss;
    const uint keep0 = pk2(c[kb8 + 4*h5 + 0], c[kb8 + 4*h5 + 1]);
    const uint keep1 = pk2(c[kb8 + 4*h5 + 2], c[kb8 + 4*h5 + 3]);
    const int  o     = kb8 + 4*(1 - h5);
    const uint send0 = pk2(c[o + 0], c[o + 1]);
    const uint send1 = pk2(c[o + 2], c[o + 3]);
    const uint recv0 = (uint)__shfl_xor((int)send0, 32, 64);
    const uint recv1 = (uint)__shfl_xor((int)send1, 32, 64);
    union { uint u[4]; f16x8 v; } A;
    A.u[0] = h5 ? recv0 : keep0;
    A.u[1] = h5 ? recv1 : keep1;
    A.u[2] = h5 ? keep0 : recv0;
    A.u[3] = h5 ? keep1 : recv1;
    return A.v;
}

// ---------------- prep: weights & bias into coalesced fragment-tiled order (verified R6) ----------------
__global__ void lwa_prep(const float* __restrict__ qkvw, const float* __restrict__ projw,
                         const float* __restrict__ table, const int* __restrict__ ridx,
                         ushort* __restrict__ wqs, ushort* __restrict__ wps, float* __restrict__ biasr)
{
    int i = blockIdx.x * 256 + threadIdx.x;
    if (i < 196608) {                       // qkv weights: rb 0..7 q (scaled), 8..15 k, 16..23 v
        int j    = i & 7;
        int lane = (i >> 3) & 63;
        int ks   = (i >> 9) & 15;
        int rb   = i >> 13;
        int row  = rb * 32 + (lane & 31);
        int col  = ks * 16 + (lane >> 5) * 8 + j;
        float v = qkvw[row * 256 + col];
        if (rb < 8) v *= SCALE_Q;
        wqs[i] = f2h_bits(v);
    } else if (i < 262144) {                // proj weights
        int t    = i - 196608;
        int j    = t & 7;
        int lane = (t >> 3) & 63;
        int ks   = (t >> 9) & 15;
        int h    = t >> 13;
        int row  = h * 32 + (lane & 31);
        int col  = ks * 16 + (lane >> 5) * 8 + j;
        wps[t] = f2h_bits(projw[row * 256 + col]);
    } else {                                // bias, fragment order [h][mt][nt][q4][lane][4]
        int t    = i - 262144;
        int j    = t & 3;
        int lane = (t >> 2) & 63;
        int q4   = (t >> 8) & 3;
        int nt   = (t >> 10) & 1;
        int mt   = (t >> 11) & 1;
        int h    = t >> 12;
        int qrow = 32 * nt + (lane & 31);
        int kv   = 32 * mt + 8 * q4 + j + 4 * (lane >> 5);
        biasr[t] = table[ridx[qrow * 64 + kv] * 8 + h];
    }
}

// ---------------- main: one block (512 thr, 8 waves = 8 heads) per window ----------------
__global__ __launch_bounds__(512, 4) void lwa_main(
    const float* __restrict__ x, const float* __restrict__ nz,
    const float* __restrict__ gamma, const float* __restrict__ beta,
    const ushort* __restrict__ wqs, const ushort* __restrict__ wps,
    const float* __restrict__ biasr, const float* __restrict__ projb,
    float* __restrict__ out)
{
    extern __shared__ char smem[];
    const int tid  = threadIdx.x;
    const int h    = tid >> 6;       // wave id == head
    const int lane = tid & 63;
    const int l31  = lane & 31;
    const int h5   = lane >> 5;
    const int w    = blockIdx.x;     // window
    const int bidx = w >> 8;
    const int kb   = h5 * 8;

    // ---- Phase 1: LN -> xn fp16 at [0, 33792) ----
    {
        const int p   = tid >> 3;
        const int sub = tid & 7;
        const float* xrow = x  + (size_t)w * 16384 + p * 256;
        const float* nrow = nz + (size_t)bidx * 16384 + p * 256;
        f32x4 v[8];
        float s = 0.f, ss = 0.f;
#pragma unroll
        for (int i = 0; i < 8; ++i) {
            const int c4 = sub + 8 * i;
            f32x4 xv = *(const f32x4*)(xrow + 4 * c4);
            f32x4 nv = *(const f32x4*)(nrow + 4 * c4);
            f32x4 t = xv * nv;
            v[i] = t;
            s  += t[0] + t[1] + t[2] + t[3];
            ss += t[0]*t[0] + t[1]*t[1] + t[2]*t[2] + t[3]*t[3];
        }
#pragma unroll
        for (int m = 1; m < 8; m <<= 1) { s += __shfl_xor(s, m, 64); ss += __shfl_xor(ss, m, 64); }
        const float mu = s * (1.f / 256.f);
        const float rs = rsqrtf(fmaxf(ss * (1.f / 256.f) - mu * mu, 0.f) + 1e-5f);
        char* xnrow = smem + (size_t)p * (XN_ROW * 2);
#pragma unroll
        for (int i = 0; i < 8; ++i) {
            const int c4 = sub + 8 * i;
            f32x4 g  = *(const f32x4*)(gamma + 4 * c4);
            f32x4 bb = *(const f32x4*)(beta  + 4 * c4);
            f32x4 t  = v[i];
            u32x2 pkv;
            pkv[0] = pk2((t[0]-mu)*rs*g[0] + bb[0], (t[1]-mu)*rs*g[1] + bb[1]);
            pkv[1] = pk2((t[2]-mu)*rs*g[2] + bb[2], (t[3]-mu)*rs*g[3] + bb[3]);
            *(u32x2*)(xnrow + c4 * 8) = pkv;
        }
    }
    __syncthreads();   // B1: xn ready

    const char* xb = smem;

    // ---- Phase 2a: q^T (swapped) + k (normal), 4-acc ILP; k -> LDS, qf -> regs ----
    f16x8 qf[2][2];
    {
        const ushort* bqp = wqs + (size_t)h * 8192;          // 16*64*8
        const ushort* bkp = wqs + (size_t)(8 + h) * 8192;
        f32x16 cq0 = Z16, cq1 = Z16, ck0 = Z16, ck1 = Z16;
#pragma unroll 4
        for (int ks = 0; ks < 16; ++ks) {
            const int kk = ks * 16 + kb;
            f16x8 a0 = *(const f16x8*)(xb + ( l31       * XN_ROW + kk) * 2);
            f16x8 a1 = *(const f16x8*)(xb + ((32 + l31) * XN_ROW + kk) * 2);
            f16x8 bq = *(const f16x8*)(bqp + (ks * 64 + lane) * 8);
            f16x8 bk = *(const f16x8*)(bkp + (ks * 64 + lane) * 8);
            cq0 = MFMA16(bq, a0, cq0, 0, 0, 0);   // D[chan][qpos 0..31]
            cq1 = MFMA16(bq, a1, cq1, 0, 0, 0);   // D[chan][qpos 32..63]
            ck0 = MFMA16(a0, bk, ck0, 0, 0, 0);   // D[kv 0..31][chan]
            ck1 = MFMA16(a1, bk, ck1, 0, 0, 0);   // D[kv 32..63][chan]
        }
        // k -> LDS [64][264], head cols 32h (disjoint from xn region; wave-local reads)
        char* kreg = smem + K_OFF;
#pragma unroll
        for (int r = 0; r < 16; ++r) {
            const int row = (r & 3) + 8 * (r >> 2) + 4 * h5;
            *(ushort*)(kreg + ( row       * XN_ROW + 32 * h + l31) * 2) = f2h_bits(ck0[r]);
            *(ushort*)(kreg + ((32 + row) * XN_ROW + 32 * h + l31) * 2) = f2h_bits(ck1[r]);
        }
        qf[0][0] = build_frag(cq0, 0, h5);
        qf[0][1] = build_frag(cq0, 1, h5);
        qf[1][0] = build_frag(cq1, 0, h5);
        qf[1][1] = build_frag(cq1, 1, h5);
    }

    // ---- Phase 2b: v (normal), 2 accs ----
    f32x16 cv0 = Z16, cv1 = Z16;
    {
        const ushort* bvp = wqs + (size_t)(16 + h) * 8192;
#pragma unroll 4
        for (int ks = 0; ks < 16; ++ks) {
            const int kk = ks * 16 + kb;
            f16x8 a0 = *(const f16x8*)(xb + ( l31       * XN_ROW + kk) * 2);
            f16x8 a1 = *(const f16x8*)(xb + ((32 + l31) * XN_ROW + kk) * 2);
            f16x8 bv = *(const f16x8*)(bvp + (ks * 64 + lane) * 8);
            cv0 = MFMA16(a0, bv, cv0, 0, 0, 0);   // D[kv 0..31][chan]
            cv1 = MFMA16(a1, bv, cv1, 0, 0, 0);   // D[kv 32..63][chan]
        }
    }
    __syncthreads();   // B2: xn dead everywhere -> vT may overwrite it

    // vT -> LDS [256][72]: row = 32h + chan(l31), cols = kv (wave-local reads)
    {
        char* vrow = smem + VT_OFF + (size_t)(32 * h + l31) * (VT_ROW * 2);
#pragma unroll
        for (int sg = 0; sg < 4; ++sg) {
            u32x2 p0, p1;
            p0[0] = pk2(cv0[4*sg+0], cv0[4*sg+1]);
            p0[1] = pk2(cv0[4*sg+2], cv0[4*sg+3]);
            *(u32x2*)(vrow + (     8 * sg + 4 * h5) * 2) = p0;
            p1[0] = pk2(cv1[4*sg+0], cv1[4*sg+1]);
            p1[1] = pk2(cv1[4*sg+2], cv1[4*sg+3]);
            *(u32x2*)(vrow + (32 + 8 * sg + 4 * h5) * 2) = p1;
        }
    }

    // ---- Phase 3: QK^T (A=k from LDS, B=qf), bias, softmax, pack P ----
    f16x8 pf[4][2];
    {
        f32x16 st[2][2] = {{Z16, Z16}, {Z16, Z16}};   // [mt(kv-half)][nt(q-half)]
        const char* kb_ = smem + K_OFF;
#pragma unroll
        for (int mt = 0; mt < 2; ++mt)
#pragma unroll
        for (int ks = 0; ks < 2; ++ks) {
            f16x8 kfr = *(const f16x8*)(kb_ + ((32 * mt + l31) * XN_ROW + 32 * h + ks * 16 + kb) * 2);
            st[mt][0] = MFMA16(kfr, qf[0][ks], st[mt][0], 0, 0, 0);
            st[mt][1] = MFMA16(kfr, qf[1][ks], st[mt][1], 0, 0, 0);
        }
#pragma unroll
        for (int mt = 0; mt < 2; ++mt)
#pragma unroll
        for (int nt = 0; nt < 2; ++nt) {
            const float* bp = biasr + (size_t)(((h * 2 + mt) * 2 + nt) * 4) * 256;
#pragma unroll
            for (int q4 = 0; q4 < 4; ++q4) {
                f32x4 bv = *(const f32x4*)(bp + (q4 * 64 + lane) * 4);
#pragma unroll
                for (int j = 0; j < 4; ++j) st[mt][nt][4*q4+j] += bv[j];
            }
        }
#pragma unroll
        for (int nt = 0; nt < 2; ++nt) {
            float mx = st[0][nt][0];
#pragma unroll
            for (int r = 0; r < 16; ++r) { mx = fmaxf(mx, st[0][nt][r]); mx = fmaxf(mx, st[1][nt][r]); }
            mx = fmaxf(mx, __shfl_xor(mx, 32, 64));
            float sum = 0.f;
#pragma unroll
            for (int r = 0; r < 16; ++r) {
                float e0 = __expf(st[0][nt][r] - mx);
                float e1 = __expf(st[1][nt][r] - mx);
                st[0][nt][r] = e0; st[1][nt][r] = e1;
                sum += e0 + e1;
            }
            sum += __shfl_xor(sum, 32, 64);
            const float rd = __builtin_amdgcn_rcpf(sum);
#pragma unroll
            for (int r = 0; r < 16; ++r) { st[0][nt][r] *= rd; st[1][nt][r] *= rd; }
            pf[0][nt] = build_frag(st[0][nt], 0, h5);
            pf[1][nt] = build_frag(st[0][nt], 1, h5);
            pf[2][nt] = build_frag(st[1][nt], 0, h5);
            pf[3][nt] = build_frag(st[1][nt], 1, h5);
        }
    }

    // ---- PV: B=vT rows (wave-local) ----
    f32x16 o0 = Z16, o1 = Z16;
    {
        const char* vrow = smem + VT_OFF + (size_t)(32 * h + l31) * (VT_ROW * 2);
#pragma unroll
        for (int c = 0; c < 4; ++c) {
            f16x8 vf = *(const f16x8*)(vrow + (c * 16 + kb) * 2);
            o0 = MFMA16(pf[c][0], vf, o0, 0, 0, 0);   // D[qpos 0..31][chan]
            o1 = MFMA16(pf[c][1], vf, o1, 0, 0, 0);   // D[qpos 32..63][chan]
        }
    }
    __syncthreads();   // B3: all PV reads of vT done -> ao may overwrite

    // ao -> LDS [64][264] at [0, 33792)
    {
        char* ao = smem + AO_OFF;
#pragma unroll
        for (int r = 0; r < 16; ++r) {
            const int row = (r & 3) + 8 * (r >> 2) + 4 * h5;
            *(ushort*)(ao + ( row       * XN_ROW + 32 * h + l31) * 2) = f2h_bits(o0[r]);
            *(ushort*)(ao + ((32 + row) * XN_ROW + 32 * h + l31) * 2) = f2h_bits(o1[r]);
        }
    }
    __syncthreads();   // B4: ao ready

    // ---- Phase 4: proj GEMM + bias ----
    {
        const ushort* bwp = wps + (size_t)h * 8192;
        const char* ao = smem + AO_OFF;
        f32x16 pa0 = Z16, pa1 = Z16;
#pragma unroll 4
        for (int ks = 0; ks < 16; ++ks) {
            const int kk = ks * 16 + kb;
            f16x8 a0 = *(const f16x8*)(ao + ( l31       * XN_ROW + kk) * 2);
            f16x8 a1 = *(const f16x8*)(ao + ((32 + l31) * XN_ROW + kk) * 2);
            f16x8 bw = *(const f16x8*)(bwp + (ks * 64 + lane) * 8);
            pa0 = MFMA16(a0, bw, pa0, 0, 0, 0);
            pa1 = MFMA16(a1, bw, pa1, 0, 0, 0);
        }
        const float pb = projb[32 * h + l31];
        float* orow = out + (size_t)w * 16384;
#pragma unroll
        for (int r = 0; r < 16; ++r) {
            const int prow = (r & 3) + 8 * (r >> 2) + 4 * h5;
            orow[(size_t)prow * 256 + 32 * h + l31] = pa0[r] + pb;
        }
#pragma unroll
        for (int r = 0; r < 16; ++r) {
            const int prow = 32 + (r & 3) + 8 * (r >> 2) + 4 * h5;
            orow[(size_t)prow * 256 + 32 * h + l31] = pa1[r] + pb;
        }
    }
}

extern "C" void kernel_launch(void* const* d_in, const int* in_sizes, int n_in,
                              void* d_out, int out_size, void* d_ws, size_t ws_size,
                              hipStream_t stream)
{
    const float* x     = (const float*)d_in[0];
    const float* nz    = (const float*)d_in[1];
    const float* gamma = (const float*)d_in[2];
    const float* beta  = (const float*)d_in[3];
    const float* qkvw  = (const float*)d_in[4];
    const float* projw = (const float*)d_in[5];
    const float* projb = (const float*)d_in[6];
    const float* table = (const float*)d_in[7];
    const int*   ridx  = (const int*)d_in[8];

    ushort* wqs   = (ushort*)d_ws;            // 196608 fp16, fragment-tiled
    ushort* wps   = wqs + 196608;             // 65536 fp16
    float*  biasr = (float*)(wps + 65536);    // 32768 f32

    (void)hipFuncSetAttribute((const void*)lwa_main,
                              hipFuncAttributeMaxDynamicSharedMemorySize, LDS_TOTAL);

    lwa_prep<<<1152, 256, 0, stream>>>(qkvw, projw, table, ridx, wqs, wps, biasr);
    lwa_main<<<2048, 512, LDS_TOTAL, stream>>>(x, nz, gamma, beta, wqs, wps, biasr, projb,
                                               (float*)d_out);
}